// Round 3
// baseline (8442.149 us; speedup 1.0000x reference)
//
#include <hip/hip_runtime.h>
#include <cstdint>
#include <cstddef>

// ---------------------------------------------------------------------------
// Round 2: fp32, batch-chunked. Changes vs round 1:
//  * lstm_rec2: quad-split recurrence — thread (j,q) computes all 4 gates of
//    unit j over K-slice [32q,32q+32); shuffle-reduce across quad (no barrier);
//    double-buffered padded h in LDS -> ONE barrier/step; xg prefetch; hout
//    stores batched 8/step-drain; exp-based tanh.
//  * gemm_tile: 128x128 tile, 8x8 acc/thread (was 128x64, 8x4).
//  * chunk candidates extended to 512/256.
// ---------------------------------------------------------------------------

constexpr int Bn   = 512;
constexpr int Cn   = 271;
constexpr int Tn   = 281;
constexpr int Hn   = 128;
constexpr int NCLS = 1854;
constexpr int Gn   = 4 * Hn;    // 512

#define DEVINL __device__ __forceinline__

DEVINL float sigm(float x)       { return 1.f / (1.f + __expf(-x)); }
DEVINL float tanhf_fast(float x) { return 2.f / (1.f + __expf(-2.f * x)) - 1.f; }

// ---------------------------------------------------------------------------
// fp32 tiled GEMM: C[m][n] = act( sum_k A(m,k)*B(k,n) + bias1 + bias2 )
// Tile 128(M) x 128(N), K-chunks of 8, 256 threads, 8x8 acc/thread.
// AMODE 0: A row-major [M][K], K%4==0.  AMODE 1: A(m,k)=X[(m/T)*C*T + k*T + m%T].
// BMODE 0: B [N][K] (A@B^T).            BMODE 1: B [K][N].
// ACT 1: tanh. NBIAS: number of bias vectors.
// ---------------------------------------------------------------------------
template <int AMODE, int BMODE, int ACT, int NBIAS>
__global__ __launch_bounds__(256, 4) void gemm_tile(
    const float* __restrict__ A, const float* __restrict__ Bm,
    const float* __restrict__ bias1, const float* __restrict__ bias2,
    float* __restrict__ Cout, int Mdim, int Ndim, int Kdim, int ldc)
{
  __shared__ __align__(16) float As[8][128];
  __shared__ __align__(16) float Bs[8][128];

  const int tid  = threadIdx.x;
  const int tx   = tid & 15;     // 16 col groups of 8
  const int ty   = tid >> 4;     // 16 row groups of 8
  const int row0 = blockIdx.x * 128;
  const int col0 = blockIdx.y * 128;

  float acc[8][8];
#pragma unroll
  for (int i = 0; i < 8; i++)
#pragma unroll
    for (int j = 0; j < 8; j++) acc[i][j] = 0.f;

  for (int k0 = 0; k0 < Kdim; k0 += 8) {
    // ---- A tile (128 rows x 8 k) ----
    if (AMODE == 0) {
      const int q  = tid >> 7;          // 0..1
      const int r  = tid & 127;
      const int gr = row0 + r;
      const int gk = k0 + q * 4;
      float4 v = make_float4(0.f, 0.f, 0.f, 0.f);
      if (gr < Mdim && gk + 3 < Kdim)
        v = *(const float4*)&A[(size_t)gr * Kdim + gk];
      As[q * 4 + 0][r] = v.x;
      As[q * 4 + 1][r] = v.y;
      As[q * 4 + 2][r] = v.z;
      As[q * 4 + 3][r] = v.w;
    } else {
#pragma unroll
      for (int l = 0; l < 4; l++) {
        const int e  = tid + l * 256;
        const int r  = e & 127;
        const int kk = e >> 7;
        const int gr = row0 + r;
        const int gk = k0 + kk;
        float v = 0.f;
        if (gr < Mdim && gk < Kdim) {
          const int bb = gr / Tn;
          const int tt = gr - bb * Tn;
          v = A[((size_t)bb * Cn + gk) * Tn + tt];  // coalesced over tt
        }
        As[kk][r] = v;
      }
    }
    // ---- B tile (8 k x 128 n) ----
#pragma unroll
    for (int l = 0; l < 4; l++) {
      const int e = tid + l * 256;
      int kk, cc;
      if (BMODE == 0) { kk = e & 7;   cc = e >> 3; }   // coalesce over k
      else            { cc = e & 127; kk = e >> 7; }   // coalesce over n
      const int gn = col0 + cc;
      const int gk = k0 + kk;
      float v = 0.f;
      if (gn < Ndim && gk < Kdim)
        v = (BMODE == 0) ? Bm[(size_t)gn * Kdim + gk]
                         : Bm[(size_t)gk * Ndim + gn];
      Bs[kk][cc] = v;
    }
    __syncthreads();
    // ---- compute: 8 kk x 64 FMA ----
#pragma unroll
    for (int kk = 0; kk < 8; kk++) {
      const float4 a0 = *(const float4*)&As[kk][ty * 8];
      const float4 a1 = *(const float4*)&As[kk][ty * 8 + 4];
      const float4 b0 = *(const float4*)&Bs[kk][tx * 8];
      const float4 b1 = *(const float4*)&Bs[kk][tx * 8 + 4];
      const float av[8] = {a0.x, a0.y, a0.z, a0.w, a1.x, a1.y, a1.z, a1.w};
      const float bv[8] = {b0.x, b0.y, b0.z, b0.w, b1.x, b1.y, b1.z, b1.w};
#pragma unroll
      for (int i = 0; i < 8; i++)
#pragma unroll
        for (int j = 0; j < 8; j++) acc[i][j] = fmaf(av[i], bv[j], acc[i][j]);
    }
    __syncthreads();
  }
  // ---- epilogue ----
#pragma unroll
  for (int i = 0; i < 8; i++) {
    const int gr = row0 + ty * 8 + i;
    if (gr >= Mdim) continue;
    const size_t rowoff = (size_t)gr * ldc;
#pragma unroll
    for (int j = 0; j < 8; j++) {
      const int gn = col0 + tx * 8 + j;
      if (gn >= Ndim) continue;
      float v = acc[i][j];
      if (NBIAS >= 1) v += bias1[gn];
      if (NBIAS >= 2) v += bias2[gn];
      if (ACT == 1) v = tanhf_fast(v);
      Cout[rowoff + gn] = v;
    }
  }
}

// ---------------------------------------------------------------------------
// LSTM recurrence v2, quad-split. grid (Bc, 2), block 512 = one batch row.
// Thread n: unit j = n>>2, K-slice q = n&3. Holds w_hh[4 gates][32 k] in
// 128 VGPRs. Per step: 128 FMA in 4 chains; quad shuffle-reduce; redundant
// state update; ONE barrier (double-buffered padded h in LDS).
// xw: [2][MC][512] chunk-local (b_ih+b_hh folded in). hout: [MC][256].
// ---------------------------------------------------------------------------
__global__ __launch_bounds__(512) void lstm_rec2(
    const float* __restrict__ xw,
    const float* __restrict__ whhf,
    const float* __restrict__ whhb,
    float* __restrict__ hout, int MC)
{
  const int dir = blockIdx.y;
  const int row = blockIdx.x;
  const int n   = threadIdx.x;
  const int j   = n >> 2;     // unit 0..127
  const int q   = n & 3;      // K-slice
  const float* __restrict__ whh = dir ? whhb : whhf;
  const float* __restrict__ xwd = xw + (size_t)dir * MC * Gn;

  // h double buffer, padded +4 words per 32 (slice q at word 36q): no bank
  // aliasing between slices. Element k lives at k + (k>>5)*4.
  __shared__ __align__(16) float hl[2][140];

  // w_hh rows {g*128+j}, cols [32q, 32q+32) -> 128 VGPRs
  float w[4][32];
#pragma unroll
  for (int g = 0; g < 4; g++) {
    const float4* wp = (const float4*)&whh[((size_t)(g * Hn + j)) * Hn + 32 * q];
#pragma unroll
    for (int i = 0; i < 8; i++) {
      const float4 v = wp[i];
      w[g][4 * i + 0] = v.x; w[g][4 * i + 1] = v.y;
      w[g][4 * i + 2] = v.z; w[g][4 * i + 3] = v.w;
    }
  }
  if (n < 140) hl[0][n] = 0.f;
  float c = 0.f;
  float hbuf[8];
  const size_t srow = (size_t)row * Tn;
  float* __restrict__ hop = hout + srow * 256 + dir * Hn + j;   // +t*256
  const int jpad = j + ((j >> 5) << 2);

  // first step's xg (gate q*128+j)
  {
    const int t0 = dir ? (Tn - 1) : 0;
  }
  float xg = xwd[(srow + (dir ? (Tn - 1) : 0)) * Gn + q * Hn + j];
  __syncthreads();

  for (int s = 0; s < Tn; s++) {
    const int p = s & 1;
    // prefetch next step's xg (latency spans the whole step)
    float xgn = 0.f;
    if (s + 1 < Tn) {
      const int tn_ = dir ? (Tn - 2 - s) : (s + 1);
      xgn = xwd[(srow + tn_) * Gn + q * Hn + j];
    }
    // matvec over K-slice: 4 gate chains x 32 FMA
    float a0 = 0.f, a1 = 0.f, a2 = 0.f, a3 = 0.f;
    const float* hs = &hl[p][36 * q];
#pragma unroll
    for (int i = 0; i < 8; i++) {
      const float4 h4 = *(const float4*)&hs[4 * i];
      a0 = fmaf(w[0][4 * i + 0], h4.x, a0);
      a0 = fmaf(w[0][4 * i + 1], h4.y, a0);
      a0 = fmaf(w[0][4 * i + 2], h4.z, a0);
      a0 = fmaf(w[0][4 * i + 3], h4.w, a0);
      a1 = fmaf(w[1][4 * i + 0], h4.x, a1);
      a1 = fmaf(w[1][4 * i + 1], h4.y, a1);
      a1 = fmaf(w[1][4 * i + 2], h4.z, a1);
      a1 = fmaf(w[1][4 * i + 3], h4.w, a1);
      a2 = fmaf(w[2][4 * i + 0], h4.x, a2);
      a2 = fmaf(w[2][4 * i + 1], h4.y, a2);
      a2 = fmaf(w[2][4 * i + 2], h4.z, a2);
      a2 = fmaf(w[2][4 * i + 3], h4.w, a2);
      a3 = fmaf(w[3][4 * i + 0], h4.x, a3);
      a3 = fmaf(w[3][4 * i + 1], h4.y, a3);
      a3 = fmaf(w[3][4 * i + 2], h4.z, a3);
      a3 = fmaf(w[3][4 * i + 3], h4.w, a3);
    }
    // add xw (gate q) exactly once per quad, then butterfly-reduce each gate
    a0 += (q == 0) ? xg : 0.f;
    a1 += (q == 1) ? xg : 0.f;
    a2 += (q == 2) ? xg : 0.f;
    a3 += (q == 3) ? xg : 0.f;
    a0 += __shfl_xor(a0, 1); a0 += __shfl_xor(a0, 2);
    a1 += __shfl_xor(a1, 1); a1 += __shfl_xor(a1, 2);
    a2 += __shfl_xor(a2, 1); a2 += __shfl_xor(a2, 2);
    a3 += __shfl_xor(a3, 1); a3 += __shfl_xor(a3, 2);
    // state update (redundant in quad; bitwise-identical inputs)
    const float iv = sigm(a0);
    const float fv = sigm(a1);
    const float gv = tanhf_fast(a2);
    const float ov = sigm(a3);
    c = fv * c + iv * gv;
    const float hv = ov * tanhf_fast(c);
    if (q == 0) hl[p ^ 1][jpad] = hv;
    hbuf[s & 7] = hv;
    // batched hout stores: one vmcnt-drain worth every 8 steps
    if ((s & 7) == 7 && q == 0) {
      const int sb = s - 7;
#pragma unroll
      for (int u = 0; u < 8; u++) {
        const int ss = sb + u;
        const int tt = dir ? (Tn - 1 - ss) : ss;
        hop[(size_t)tt * 256] = hbuf[u];
      }
    }
    __syncthreads();
    xg = xgn;
  }
  // tail store (Tn = 281 = 35*8 + 1; s=280 -> hbuf[0])
  if (q == 0) {
    const int tt = dir ? 0 : (Tn - 1);
    hop[(size_t)tt * 256] = hbuf[0];
  }
}

// ---------------------------------------------------------------------------
// a[m] = u[m][0:256] . v[0:256] — one wave per row.
// ---------------------------------------------------------------------------
__global__ __launch_bounds__(256) void dot_v_kernel(
    const float* __restrict__ u, const float* __restrict__ v,
    float* __restrict__ a, int MC)
{
  const int lane = threadIdx.x & 63;
  const int row  = blockIdx.x * 4 + (threadIdx.x >> 6);
  if (row >= MC) return;
  const float4 uv = ((const float4*)(u + (size_t)row * 256))[lane];
  const float4 vv = ((const float4*)v)[lane];
  float p = uv.x * vv.x + uv.y * vv.y + uv.z * vv.z + uv.w * vv.w;
#pragma unroll
  for (int off = 32; off > 0; off >>= 1) p += __shfl_down(p, off);
  if (lane == 0) a[row] = p;
}

// ---------------------------------------------------------------------------
// softmax over T + pooling (chunk-local).
// ---------------------------------------------------------------------------
__global__ __launch_bounds__(256) void attn_pool(
    const float* __restrict__ a, const float* __restrict__ h1,
    float* __restrict__ wout)
{
  const int b    = blockIdx.x;
  const int tid  = threadIdx.x;
  const int lane = tid & 63;
  const int wid  = tid >> 6;
  __shared__ float sa[Tn];
  __shared__ float red[8];

  float lmax = -3.4e38f;
  for (int t = tid; t < Tn; t += 256) {
    const float x = a[(size_t)b * Tn + t];
    sa[t] = x;
    lmax  = fmaxf(lmax, x);
  }
#pragma unroll
  for (int off = 1; off < 64; off <<= 1) lmax = fmaxf(lmax, __shfl_xor(lmax, off));
  if (lane == 0) red[wid] = lmax;
  __syncthreads();
  const float bmax = fmaxf(fmaxf(red[0], red[1]), fmaxf(red[2], red[3]));

  float lsum = 0.f;
  for (int t = tid; t < Tn; t += 256) {
    const float e = __expf(sa[t] - bmax);
    sa[t] = e;
    lsum += e;
  }
#pragma unroll
  for (int off = 1; off < 64; off <<= 1) lsum += __shfl_xor(lsum, off);
  if (lane == 0) red[4 + wid] = lsum;
  __syncthreads();
  const float inv = 1.f / (red[4] + red[5] + red[6] + red[7]);

  float acc = 0.f;
  const float* hb = h1 + (size_t)b * Tn * 256 + tid;
  for (int t = 0; t < Tn; t++) acc += sa[t] * hb[(size_t)t * 256];
  wout[(size_t)b * 256 + tid] = acc * inv;
}

// ---------------------------------------------------------------------------
extern "C" void kernel_launch(void* const* d_in, const int* in_sizes, int n_in,
                              void* d_out, int out_size, void* d_ws, size_t ws_size,
                              hipStream_t stream)
{
  const float* X      = (const float*)d_in[0];
  const float* w_ih0f = (const float*)d_in[1];
  const float* w_hh0f = (const float*)d_in[2];
  const float* b_ih0f = (const float*)d_in[3];
  const float* b_hh0f = (const float*)d_in[4];
  const float* w_ih0b = (const float*)d_in[5];
  const float* w_hh0b = (const float*)d_in[6];
  const float* b_ih0b = (const float*)d_in[7];
  const float* b_hh0b = (const float*)d_in[8];
  const float* w_ih1f = (const float*)d_in[9];
  const float* w_hh1f = (const float*)d_in[10];
  const float* b_ih1f = (const float*)d_in[11];
  const float* b_hh1f = (const float*)d_in[12];
  const float* w_ih1b = (const float*)d_in[13];
  const float* w_hh1b = (const float*)d_in[14];
  const float* b_ih1b = (const float*)d_in[15];
  const float* b_hh1b = (const float*)d_in[16];
  const float* att_W  = (const float*)d_in[17];
  const float* att_v  = (const float*)d_in[18];
  const float* head_W = (const float*)d_in[19];
  const float* head_b = (const float*)d_in[20];

  // largest chunk size fitting ws_size (deterministic across calls)
  int Bc = 8;
  {
    const int cands[7] = {512, 256, 128, 64, 32, 16, 8};
    for (int i = 0; i < 7; i++) {
      const size_t mc   = (size_t)cands[i] * Tn;
      const size_t need = 4ull * ((size_t)512 * 256 + mc * 1537);
      if (need <= ws_size) { Bc = cands[i]; break; }
    }
  }
  const size_t MCs = (size_t)Bc * Tn;
  const int    MC  = (int)MCs;

  float* wgt = (float*)d_ws;               // [512][256] persistent
  float* xwc = wgt + (size_t)512 * 256;    // [2][MC][512]
  float* h0c = xwc + 2 * MCs * Gn;         // [MC][256]
  float* h1c = h0c + MCs * 256;            // [MC][256]
  float* ac  = h1c + MCs * 256;            // [MC]
  float* u   = xwc;                        // reuse (xw dead by phase 5)

  const dim3 blk(256);
  const int  mt = (MC + 127) / 128;
  const dim3 gXW(mt, Gn / 128);            // (., 4)
  const dim3 gU(mt, 256 / 128);            // (., 2)
  const int  nch = Bn / Bc;

  for (int ch = 0; ch < nch; ch++) {
    const float* Xc   = X + (size_t)ch * Bc * Cn * Tn;
    float*       wgtc = wgt + (size_t)ch * Bc * 256;

    // 1) layer-0 input projections (transpose fused), both biases folded
    gemm_tile<1, 0, 0, 2><<<gXW, blk, 0, stream>>>(Xc, w_ih0f, b_ih0f, b_hh0f,
                                                   xwc, MC, Gn, Cn, Gn);
    gemm_tile<1, 0, 0, 2><<<gXW, blk, 0, stream>>>(Xc, w_ih0b, b_ih0b, b_hh0b,
                                                   xwc + MCs * Gn, MC, Gn, Cn, Gn);
    // 2) layer-0 recurrence
    lstm_rec2<<<dim3(Bc, 2), dim3(512), 0, stream>>>(xwc, w_hh0f, w_hh0b, h0c, MC);
    // 3) layer-1 input projections
    gemm_tile<0, 0, 0, 2><<<gXW, blk, 0, stream>>>(h0c, w_ih1f, b_ih1f, b_hh1f,
                                                   xwc, MC, Gn, 256, Gn);
    gemm_tile<0, 0, 0, 2><<<gXW, blk, 0, stream>>>(h0c, w_ih1b, b_ih1b, b_hh1b,
                                                   xwc + MCs * Gn, MC, Gn, 256, Gn);
    // 4) layer-1 recurrence
    lstm_rec2<<<dim3(Bc, 2), dim3(512), 0, stream>>>(xwc, w_hh1f, w_hh1b, h1c, MC);
    // 5) u = tanh(h1 @ att_W)
    gemm_tile<0, 1, 1, 0><<<gU, blk, 0, stream>>>(h1c, att_W, nullptr, nullptr,
                                                  u, MC, 256, 256, 256);
    // 6) a = u . att_v
    dot_v_kernel<<<dim3((MC + 3) / 4), blk, 0, stream>>>(u, att_v, ac, MC);
    // 7) softmax + pooling into this chunk's wgt slice
    attn_pool<<<dim3(Bc), blk, 0, stream>>>(ac, h1c, wgtc);
  }
  // 8) head
  gemm_tile<0, 0, 0, 1><<<dim3((Bn + 127) / 128, (NCLS + 127) / 128), blk, 0, stream>>>(
      wgt, head_W, head_b, nullptr, (float*)d_out, Bn, NCLS, 256, NCLS);
}

// Round 4
// 6420.505 us; speedup vs baseline: 1.3149x; 1.3149x over previous
//
#include <hip/hip_runtime.h>
#include <cstdint>
#include <cstddef>

// ---------------------------------------------------------------------------
// Round 4: fp32, batch-chunked. Change vs round 3 (single, targeted):
//  * gemm_tile: __launch_bounds__(256) WITHOUT min-waves clamp. Round 3's
//    (256,4) capped VGPRs at 128 -> acc[8][8] spilled to scratch (VGPR=64,
//    2.8 GB/dispatch of HBM scratch traffic, VALUBusy 15%). 8x8 acc needs
//    ~130-160 VGPRs; let the allocator have them (3 waves/SIMD is plenty).
// Everything else identical to round 3 (lstm_rec2 quad-split recurrence etc).
// ---------------------------------------------------------------------------

constexpr int Bn   = 512;
constexpr int Cn   = 271;
constexpr int Tn   = 281;
constexpr int Hn   = 128;
constexpr int NCLS = 1854;
constexpr int Gn   = 4 * Hn;    // 512

#define DEVINL __device__ __forceinline__

DEVINL float sigm(float x)       { return 1.f / (1.f + __expf(-x)); }
DEVINL float tanhf_fast(float x) { return 2.f / (1.f + __expf(-2.f * x)) - 1.f; }

// ---------------------------------------------------------------------------
// fp32 tiled GEMM: C[m][n] = act( sum_k A(m,k)*B(k,n) + bias1 + bias2 )
// Tile 128(M) x 128(N), K-chunks of 8, 256 threads, 8x8 acc/thread.
// AMODE 0: A row-major [M][K], K%4==0.  AMODE 1: A(m,k)=X[(m/T)*C*T + k*T + m%T].
// BMODE 0: B [N][K] (A@B^T).            BMODE 1: B [K][N].
// ACT 1: tanh. NBIAS: number of bias vectors.
// ---------------------------------------------------------------------------
template <int AMODE, int BMODE, int ACT, int NBIAS>
__global__ __launch_bounds__(256) void gemm_tile(
    const float* __restrict__ A, const float* __restrict__ Bm,
    const float* __restrict__ bias1, const float* __restrict__ bias2,
    float* __restrict__ Cout, int Mdim, int Ndim, int Kdim, int ldc)
{
  __shared__ __align__(16) float As[8][128];
  __shared__ __align__(16) float Bs[8][128];

  const int tid  = threadIdx.x;
  const int tx   = tid & 15;     // 16 col groups of 8
  const int ty   = tid >> 4;     // 16 row groups of 8
  const int row0 = blockIdx.x * 128;
  const int col0 = blockIdx.y * 128;

  float acc[8][8];
#pragma unroll
  for (int i = 0; i < 8; i++)
#pragma unroll
    for (int j = 0; j < 8; j++) acc[i][j] = 0.f;

  for (int k0 = 0; k0 < Kdim; k0 += 8) {
    // ---- A tile (128 rows x 8 k) ----
    if (AMODE == 0) {
      const int q  = tid >> 7;          // 0..1
      const int r  = tid & 127;
      const int gr = row0 + r;
      const int gk = k0 + q * 4;
      float4 v = make_float4(0.f, 0.f, 0.f, 0.f);
      if (gr < Mdim && gk + 3 < Kdim)
        v = *(const float4*)&A[(size_t)gr * Kdim + gk];
      As[q * 4 + 0][r] = v.x;
      As[q * 4 + 1][r] = v.y;
      As[q * 4 + 2][r] = v.z;
      As[q * 4 + 3][r] = v.w;
    } else {
#pragma unroll
      for (int l = 0; l < 4; l++) {
        const int e  = tid + l * 256;
        const int r  = e & 127;
        const int kk = e >> 7;
        const int gr = row0 + r;
        const int gk = k0 + kk;
        float v = 0.f;
        if (gr < Mdim && gk < Kdim) {
          const int bb = gr / Tn;
          const int tt = gr - bb * Tn;
          v = A[((size_t)bb * Cn + gk) * Tn + tt];  // coalesced over tt
        }
        As[kk][r] = v;
      }
    }
    // ---- B tile (8 k x 128 n) ----
#pragma unroll
    for (int l = 0; l < 4; l++) {
      const int e = tid + l * 256;
      int kk, cc;
      if (BMODE == 0) { kk = e & 7;   cc = e >> 3; }   // coalesce over k
      else            { cc = e & 127; kk = e >> 7; }   // coalesce over n
      const int gn = col0 + cc;
      const int gk = k0 + kk;
      float v = 0.f;
      if (gn < Ndim && gk < Kdim)
        v = (BMODE == 0) ? Bm[(size_t)gn * Kdim + gk]
                         : Bm[(size_t)gk * Ndim + gn];
      Bs[kk][cc] = v;
    }
    __syncthreads();
    // ---- compute: 8 kk x 64 FMA ----
#pragma unroll
    for (int kk = 0; kk < 8; kk++) {
      const float4 a0 = *(const float4*)&As[kk][ty * 8];
      const float4 a1 = *(const float4*)&As[kk][ty * 8 + 4];
      const float4 b0 = *(const float4*)&Bs[kk][tx * 8];
      const float4 b1 = *(const float4*)&Bs[kk][tx * 8 + 4];
      const float av[8] = {a0.x, a0.y, a0.z, a0.w, a1.x, a1.y, a1.z, a1.w};
      const float bv[8] = {b0.x, b0.y, b0.z, b0.w, b1.x, b1.y, b1.z, b1.w};
#pragma unroll
      for (int i = 0; i < 8; i++)
#pragma unroll
        for (int j = 0; j < 8; j++) acc[i][j] = fmaf(av[i], bv[j], acc[i][j]);
    }
    __syncthreads();
  }
  // ---- epilogue ----
#pragma unroll
  for (int i = 0; i < 8; i++) {
    const int gr = row0 + ty * 8 + i;
    if (gr >= Mdim) continue;
    const size_t rowoff = (size_t)gr * ldc;
#pragma unroll
    for (int j = 0; j < 8; j++) {
      const int gn = col0 + tx * 8 + j;
      if (gn >= Ndim) continue;
      float v = acc[i][j];
      if (NBIAS >= 1) v += bias1[gn];
      if (NBIAS >= 2) v += bias2[gn];
      if (ACT == 1) v = tanhf_fast(v);
      Cout[rowoff + gn] = v;
    }
  }
}

// ---------------------------------------------------------------------------
// LSTM recurrence v2, quad-split. grid (Bc, 2), block 512 = one batch row.
// Thread n: unit j = n>>2, K-slice q = n&3. Holds w_hh[4 gates][32 k] in
// 128 VGPRs. Per step: 128 FMA in 4 chains; quad shuffle-reduce; redundant
// state update; ONE barrier (double-buffered padded h in LDS).
// xw: [2][MC][512] chunk-local (b_ih+b_hh folded in). hout: [MC][256].
// ---------------------------------------------------------------------------
__global__ __launch_bounds__(512) void lstm_rec2(
    const float* __restrict__ xw,
    const float* __restrict__ whhf,
    const float* __restrict__ whhb,
    float* __restrict__ hout, int MC)
{
  const int dir = blockIdx.y;
  const int row = blockIdx.x;
  const int n   = threadIdx.x;
  const int j   = n >> 2;     // unit 0..127
  const int q   = n & 3;      // K-slice
  const float* __restrict__ whh = dir ? whhb : whhf;
  const float* __restrict__ xwd = xw + (size_t)dir * MC * Gn;

  // h double buffer, padded +4 words per 32 (slice q at word 36q).
  __shared__ __align__(16) float hl[2][140];

  // w_hh rows {g*128+j}, cols [32q, 32q+32) -> 128 VGPRs
  float w[4][32];
#pragma unroll
  for (int g = 0; g < 4; g++) {
    const float4* wp = (const float4*)&whh[((size_t)(g * Hn + j)) * Hn + 32 * q];
#pragma unroll
    for (int i = 0; i < 8; i++) {
      const float4 v = wp[i];
      w[g][4 * i + 0] = v.x; w[g][4 * i + 1] = v.y;
      w[g][4 * i + 2] = v.z; w[g][4 * i + 3] = v.w;
    }
  }
  if (n < 140) hl[0][n] = 0.f;
  float c = 0.f;
  float hbuf[8];
  const size_t srow = (size_t)row * Tn;
  float* __restrict__ hop = hout + srow * 256 + dir * Hn + j;   // +t*256
  const int jpad = j + ((j >> 5) << 2);

  float xg = xwd[(srow + (dir ? (Tn - 1) : 0)) * Gn + q * Hn + j];
  __syncthreads();

  for (int s = 0; s < Tn; s++) {
    const int p = s & 1;
    // prefetch next step's xg (latency spans the whole step)
    float xgn = 0.f;
    if (s + 1 < Tn) {
      const int tn_ = dir ? (Tn - 2 - s) : (s + 1);
      xgn = xwd[(srow + tn_) * Gn + q * Hn + j];
    }
    // matvec over K-slice: 4 gate chains x 32 FMA
    float a0 = 0.f, a1 = 0.f, a2 = 0.f, a3 = 0.f;
    const float* hs = &hl[p][36 * q];
#pragma unroll
    for (int i = 0; i < 8; i++) {
      const float4 h4 = *(const float4*)&hs[4 * i];
      a0 = fmaf(w[0][4 * i + 0], h4.x, a0);
      a0 = fmaf(w[0][4 * i + 1], h4.y, a0);
      a0 = fmaf(w[0][4 * i + 2], h4.z, a0);
      a0 = fmaf(w[0][4 * i + 3], h4.w, a0);
      a1 = fmaf(w[1][4 * i + 0], h4.x, a1);
      a1 = fmaf(w[1][4 * i + 1], h4.y, a1);
      a1 = fmaf(w[1][4 * i + 2], h4.z, a1);
      a1 = fmaf(w[1][4 * i + 3], h4.w, a1);
      a2 = fmaf(w[2][4 * i + 0], h4.x, a2);
      a2 = fmaf(w[2][4 * i + 1], h4.y, a2);
      a2 = fmaf(w[2][4 * i + 2], h4.z, a2);
      a2 = fmaf(w[2][4 * i + 3], h4.w, a2);
      a3 = fmaf(w[3][4 * i + 0], h4.x, a3);
      a3 = fmaf(w[3][4 * i + 1], h4.y, a3);
      a3 = fmaf(w[3][4 * i + 2], h4.z, a3);
      a3 = fmaf(w[3][4 * i + 3], h4.w, a3);
    }
    // add xw (gate q) exactly once per quad, then butterfly-reduce each gate
    a0 += (q == 0) ? xg : 0.f;
    a1 += (q == 1) ? xg : 0.f;
    a2 += (q == 2) ? xg : 0.f;
    a3 += (q == 3) ? xg : 0.f;
    a0 += __shfl_xor(a0, 1); a0 += __shfl_xor(a0, 2);
    a1 += __shfl_xor(a1, 1); a1 += __shfl_xor(a1, 2);
    a2 += __shfl_xor(a2, 1); a2 += __shfl_xor(a2, 2);
    a3 += __shfl_xor(a3, 1); a3 += __shfl_xor(a3, 2);
    // state update (redundant in quad; bitwise-identical inputs)
    const float iv = sigm(a0);
    const float fv = sigm(a1);
    const float gv = tanhf_fast(a2);
    const float ov = sigm(a3);
    c = fv * c + iv * gv;
    const float hv = ov * tanhf_fast(c);
    if (q == 0) hl[p ^ 1][jpad] = hv;
    hbuf[s & 7] = hv;
    // batched hout stores: one vmcnt-drain worth every 8 steps
    if ((s & 7) == 7 && q == 0) {
      const int sb = s - 7;
#pragma unroll
      for (int u = 0; u < 8; u++) {
        const int ss = sb + u;
        const int tt = dir ? (Tn - 1 - ss) : ss;
        hop[(size_t)tt * 256] = hbuf[u];
      }
    }
    __syncthreads();
    xg = xgn;
  }
  // tail store (Tn = 281 = 35*8 + 1; s=280 -> hbuf[0])
  if (q == 0) {
    const int tt = dir ? 0 : (Tn - 1);
    hop[(size_t)tt * 256] = hbuf[0];
  }
}

// ---------------------------------------------------------------------------
// a[m] = u[m][0:256] . v[0:256] — one wave per row.
// ---------------------------------------------------------------------------
__global__ __launch_bounds__(256) void dot_v_kernel(
    const float* __restrict__ u, const float* __restrict__ v,
    float* __restrict__ a, int MC)
{
  const int lane = threadIdx.x & 63;
  const int row  = blockIdx.x * 4 + (threadIdx.x >> 6);
  if (row >= MC) return;
  const float4 uv = ((const float4*)(u + (size_t)row * 256))[lane];
  const float4 vv = ((const float4*)v)[lane];
  float p = uv.x * vv.x + uv.y * vv.y + uv.z * vv.z + uv.w * vv.w;
#pragma unroll
  for (int off = 32; off > 0; off >>= 1) p += __shfl_down(p, off);
  if (lane == 0) a[row] = p;
}

// ---------------------------------------------------------------------------
// softmax over T + pooling (chunk-local).
// ---------------------------------------------------------------------------
__global__ __launch_bounds__(256) void attn_pool(
    const float* __restrict__ a, const float* __restrict__ h1,
    float* __restrict__ wout)
{
  const int b    = blockIdx.x;
  const int tid  = threadIdx.x;
  const int lane = tid & 63;
  const int wid  = tid >> 6;
  __shared__ float sa[Tn];
  __shared__ float red[8];

  float lmax = -3.4e38f;
  for (int t = tid; t < Tn; t += 256) {
    const float x = a[(size_t)b * Tn + t];
    sa[t] = x;
    lmax  = fmaxf(lmax, x);
  }
#pragma unroll
  for (int off = 1; off < 64; off <<= 1) lmax = fmaxf(lmax, __shfl_xor(lmax, off));
  if (lane == 0) red[wid] = lmax;
  __syncthreads();
  const float bmax = fmaxf(fmaxf(red[0], red[1]), fmaxf(red[2], red[3]));

  float lsum = 0.f;
  for (int t = tid; t < Tn; t += 256) {
    const float e = __expf(sa[t] - bmax);
    sa[t] = e;
    lsum += e;
  }
#pragma unroll
  for (int off = 1; off < 64; off <<= 1) lsum += __shfl_xor(lsum, off);
  if (lane == 0) red[4 + wid] = lsum;
  __syncthreads();
  const float inv = 1.f / (red[4] + red[5] + red[6] + red[7]);

  float acc = 0.f;
  const float* hb = h1 + (size_t)b * Tn * 256 + tid;
  for (int t = 0; t < Tn; t++) acc += sa[t] * hb[(size_t)t * 256];
  wout[(size_t)b * 256 + tid] = acc * inv;
}

// ---------------------------------------------------------------------------
extern "C" void kernel_launch(void* const* d_in, const int* in_sizes, int n_in,
                              void* d_out, int out_size, void* d_ws, size_t ws_size,
                              hipStream_t stream)
{
  const float* X      = (const float*)d_in[0];
  const float* w_ih0f = (const float*)d_in[1];
  const float* w_hh0f = (const float*)d_in[2];
  const float* b_ih0f = (const float*)d_in[3];
  const float* b_hh0f = (const float*)d_in[4];
  const float* w_ih0b = (const float*)d_in[5];
  const float* w_hh0b = (const float*)d_in[6];
  const float* b_ih0b = (const float*)d_in[7];
  const float* b_hh0b = (const float*)d_in[8];
  const float* w_ih1f = (const float*)d_in[9];
  const float* w_hh1f = (const float*)d_in[10];
  const float* b_ih1f = (const float*)d_in[11];
  const float* b_hh1f = (const float*)d_in[12];
  const float* w_ih1b = (const float*)d_in[13];
  const float* w_hh1b = (const float*)d_in[14];
  const float* b_ih1b = (const float*)d_in[15];
  const float* b_hh1b = (const float*)d_in[16];
  const float* att_W  = (const float*)d_in[17];
  const float* att_v  = (const float*)d_in[18];
  const float* head_W = (const float*)d_in[19];
  const float* head_b = (const float*)d_in[20];

  // largest chunk size fitting ws_size (deterministic across calls)
  int Bc = 8;
  {
    const int cands[7] = {512, 256, 128, 64, 32, 16, 8};
    for (int i = 0; i < 7; i++) {
      const size_t mc   = (size_t)cands[i] * Tn;
      const size_t need = 4ull * ((size_t)512 * 256 + mc * 1537);
      if (need <= ws_size) { Bc = cands[i]; break; }
    }
  }
  const size_t MCs = (size_t)Bc * Tn;
  const int    MC  = (int)MCs;

  float* wgt = (float*)d_ws;               // [512][256] persistent
  float* xwc = wgt + (size_t)512 * 256;    // [2][MC][512]
  float* h0c = xwc + 2 * MCs * Gn;         // [MC][256]
  float* h1c = h0c + MCs * 256;            // [MC][256]
  float* ac  = h1c + MCs * 256;            // [MC]
  float* u   = xwc;                        // reuse (xw dead by phase 5)

  const dim3 blk(256);
  const int  mt = (MC + 127) / 128;
  const dim3 gXW(mt, Gn / 128);            // (., 4)
  const dim3 gU(mt, 256 / 128);            // (., 2)
  const int  nch = Bn / Bc;

  for (int ch = 0; ch < nch; ch++) {
    const float* Xc   = X + (size_t)ch * Bc * Cn * Tn;
    float*       wgtc = wgt + (size_t)ch * Bc * 256;

    // 1) layer-0 input projections (transpose fused), both biases folded
    gemm_tile<1, 0, 0, 2><<<gXW, blk, 0, stream>>>(Xc, w_ih0f, b_ih0f, b_hh0f,
                                                   xwc, MC, Gn, Cn, Gn);
    gemm_tile<1, 0, 0, 2><<<gXW, blk, 0, stream>>>(Xc, w_ih0b, b_ih0b, b_hh0b,
                                                   xwc + MCs * Gn, MC, Gn, Cn, Gn);
    // 2) layer-0 recurrence
    lstm_rec2<<<dim3(Bc, 2), dim3(512), 0, stream>>>(xwc, w_hh0f, w_hh0b, h0c, MC);
    // 3) layer-1 input projections
    gemm_tile<0, 0, 0, 2><<<gXW, blk, 0, stream>>>(h0c, w_ih1f, b_ih1f, b_hh1f,
                                                   xwc, MC, Gn, 256, Gn);
    gemm_tile<0, 0, 0, 2><<<gXW, blk, 0, stream>>>(h0c, w_ih1b, b_ih1b, b_hh1b,
                                                   xwc + MCs * Gn, MC, Gn, 256, Gn);
    // 4) layer-1 recurrence
    lstm_rec2<<<dim3(Bc, 2), dim3(512), 0, stream>>>(xwc, w_hh1f, w_hh1b, h1c, MC);
    // 5) u = tanh(h1 @ att_W)
    gemm_tile<0, 1, 1, 0><<<gU, blk, 0, stream>>>(h1c, att_W, nullptr, nullptr,
                                                  u, MC, 256, 256, 256);
    // 6) a = u . att_v
    dot_v_kernel<<<dim3((MC + 3) / 4), blk, 0, stream>>>(u, att_v, ac, MC);
    // 7) softmax + pooling into this chunk's wgt slice
    attn_pool<<<dim3(Bc), blk, 0, stream>>>(ac, h1c, wgtc);
  }
  // 8) head
  gemm_tile<0, 0, 0, 1><<<dim3((Bn + 127) / 128, (NCLS + 127) / 128), blk, 0, stream>>>(
      wgt, head_W, head_b, nullptr, (float*)d_out, Bn, NCLS, 256, NCLS);
}

// Round 5
// 6105.719 us; speedup vs baseline: 1.3827x; 1.0516x over previous
//
#include <hip/hip_runtime.h>
#include <cstdint>
#include <cstddef>

// ---------------------------------------------------------------------------
// Round 5: fp32, batch-chunked. Change vs round 4 (single, targeted):
//  * lstm_rec3: fix register spill. Round 4's lstm_rec2 showed VGPR=84 with
//    a 128-element weight array -> weights spilled to scratch (FETCH 2x ideal,
//    VALUBusy 81%, 650 us/dispatch). Fix: __launch_bounds__(512,2) raises the
//    VGPR cap to 256; 8-step unroll makes hbuf indices compile-time (round 4
//    used hbuf[s&7] with dynamic s -> scratch).
// Everything else identical to round 4.
// ---------------------------------------------------------------------------

constexpr int Bn   = 512;
constexpr int Cn   = 271;
constexpr int Tn   = 281;
constexpr int Hn   = 128;
constexpr int NCLS = 1854;
constexpr int Gn   = 4 * Hn;    // 512

#define DEVINL __device__ __forceinline__

DEVINL float sigm(float x)       { return 1.f / (1.f + __expf(-x)); }
DEVINL float tanhf_fast(float x) { return 2.f / (1.f + __expf(-2.f * x)) - 1.f; }

// ---------------------------------------------------------------------------
// fp32 tiled GEMM: C[m][n] = act( sum_k A(m,k)*B(k,n) + bias1 + bias2 )
// Tile 128(M) x 128(N), K-chunks of 8, 256 threads, 8x8 acc/thread.
// AMODE 0: A row-major [M][K], K%4==0.  AMODE 1: A(m,k)=X[(m/T)*C*T + k*T + m%T].
// BMODE 0: B [N][K] (A@B^T).            BMODE 1: B [K][N].
// ACT 1: tanh. NBIAS: number of bias vectors.
// ---------------------------------------------------------------------------
template <int AMODE, int BMODE, int ACT, int NBIAS>
__global__ __launch_bounds__(256) void gemm_tile(
    const float* __restrict__ A, const float* __restrict__ Bm,
    const float* __restrict__ bias1, const float* __restrict__ bias2,
    float* __restrict__ Cout, int Mdim, int Ndim, int Kdim, int ldc)
{
  __shared__ __align__(16) float As[8][128];
  __shared__ __align__(16) float Bs[8][128];

  const int tid  = threadIdx.x;
  const int tx   = tid & 15;     // 16 col groups of 8
  const int ty   = tid >> 4;     // 16 row groups of 8
  const int row0 = blockIdx.x * 128;
  const int col0 = blockIdx.y * 128;

  float acc[8][8];
#pragma unroll
  for (int i = 0; i < 8; i++)
#pragma unroll
    for (int j = 0; j < 8; j++) acc[i][j] = 0.f;

  for (int k0 = 0; k0 < Kdim; k0 += 8) {
    // ---- A tile (128 rows x 8 k) ----
    if (AMODE == 0) {
      const int q  = tid >> 7;          // 0..1
      const int r  = tid & 127;
      const int gr = row0 + r;
      const int gk = k0 + q * 4;
      float4 v = make_float4(0.f, 0.f, 0.f, 0.f);
      if (gr < Mdim && gk + 3 < Kdim)
        v = *(const float4*)&A[(size_t)gr * Kdim + gk];
      As[q * 4 + 0][r] = v.x;
      As[q * 4 + 1][r] = v.y;
      As[q * 4 + 2][r] = v.z;
      As[q * 4 + 3][r] = v.w;
    } else {
#pragma unroll
      for (int l = 0; l < 4; l++) {
        const int e  = tid + l * 256;
        const int r  = e & 127;
        const int kk = e >> 7;
        const int gr = row0 + r;
        const int gk = k0 + kk;
        float v = 0.f;
        if (gr < Mdim && gk < Kdim) {
          const int bb = gr / Tn;
          const int tt = gr - bb * Tn;
          v = A[((size_t)bb * Cn + gk) * Tn + tt];  // coalesced over tt
        }
        As[kk][r] = v;
      }
    }
    // ---- B tile (8 k x 128 n) ----
#pragma unroll
    for (int l = 0; l < 4; l++) {
      const int e = tid + l * 256;
      int kk, cc;
      if (BMODE == 0) { kk = e & 7;   cc = e >> 3; }   // coalesce over k
      else            { cc = e & 127; kk = e >> 7; }   // coalesce over n
      const int gn = col0 + cc;
      const int gk = k0 + kk;
      float v = 0.f;
      if (gn < Ndim && gk < Kdim)
        v = (BMODE == 0) ? Bm[(size_t)gn * Kdim + gk]
                         : Bm[(size_t)gk * Ndim + gn];
      Bs[kk][cc] = v;
    }
    __syncthreads();
    // ---- compute: 8 kk x 64 FMA ----
#pragma unroll
    for (int kk = 0; kk < 8; kk++) {
      const float4 a0 = *(const float4*)&As[kk][ty * 8];
      const float4 a1 = *(const float4*)&As[kk][ty * 8 + 4];
      const float4 b0 = *(const float4*)&Bs[kk][tx * 8];
      const float4 b1 = *(const float4*)&Bs[kk][tx * 8 + 4];
      const float av[8] = {a0.x, a0.y, a0.z, a0.w, a1.x, a1.y, a1.z, a1.w};
      const float bv[8] = {b0.x, b0.y, b0.z, b0.w, b1.x, b1.y, b1.z, b1.w};
#pragma unroll
      for (int i = 0; i < 8; i++)
#pragma unroll
        for (int j = 0; j < 8; j++) acc[i][j] = fmaf(av[i], bv[j], acc[i][j]);
    }
    __syncthreads();
  }
  // ---- epilogue ----
#pragma unroll
  for (int i = 0; i < 8; i++) {
    const int gr = row0 + ty * 8 + i;
    if (gr >= Mdim) continue;
    const size_t rowoff = (size_t)gr * ldc;
#pragma unroll
    for (int j = 0; j < 8; j++) {
      const int gn = col0 + tx * 8 + j;
      if (gn >= Ndim) continue;
      float v = acc[i][j];
      if (NBIAS >= 1) v += bias1[gn];
      if (NBIAS >= 2) v += bias2[gn];
      if (ACT == 1) v = tanhf_fast(v);
      Cout[rowoff + gn] = v;
    }
  }
}

// ---------------------------------------------------------------------------
// LSTM recurrence v3, quad-split, spill-free. grid (Bc, 2), block 512 = one
// batch row. Thread n: unit j = n>>2, K-slice q = n&3. Holds w_hh[4][32] in
// 128 VGPRs (launch_bounds (512,2) -> 256-VGPR cap, no spill). Steps unrolled
// 8x so hbuf[] indices are static. ONE barrier/step.
// xw: [2][MC][512] chunk-local (b_ih+b_hh folded in). hout: [MC][256].
// ---------------------------------------------------------------------------
__global__ __launch_bounds__(512, 2) void lstm_rec3(
    const float* __restrict__ xw,
    const float* __restrict__ whhf,
    const float* __restrict__ whhb,
    float* __restrict__ hout, int MC)
{
  const int dir = blockIdx.y;
  const int row = blockIdx.x;
  const int n   = threadIdx.x;
  const int j   = n >> 2;     // unit 0..127
  const int q   = n & 3;      // K-slice
  const float* __restrict__ whh = dir ? whhb : whhf;
  const float* __restrict__ xwd = xw + (size_t)dir * MC * Gn;

  // h double buffer, padded +4 words per 32 (slice q at word 36q).
  __shared__ __align__(16) float hl[2][140];

  // w_hh rows {g*128+j}, cols [32q, 32q+32) -> 128 VGPRs
  float w[4][32];
#pragma unroll
  for (int g = 0; g < 4; g++) {
    const float4* wp = (const float4*)&whh[((size_t)(g * Hn + j)) * Hn + 32 * q];
#pragma unroll
    for (int i = 0; i < 8; i++) {
      const float4 v = wp[i];
      w[g][4 * i + 0] = v.x; w[g][4 * i + 1] = v.y;
      w[g][4 * i + 2] = v.z; w[g][4 * i + 3] = v.w;
    }
  }
  if (n < 140) hl[0][n] = 0.f;
  float c = 0.f;
  float hbuf[8];
  const size_t srow = (size_t)row * Tn;
  float* __restrict__ hop = hout + srow * 256 + dir * Hn + j;   // +t*256
  const int jpad = j + ((j >> 5) << 2);

  float xg = xwd[(srow + (dir ? (Tn - 1) : 0)) * Gn + q * Hn + j];
  __syncthreads();

  for (int s8 = 0; s8 < Tn - 1; s8 += 8) {   // 280 steps, 35 blocks of 8
#pragma unroll
    for (int u = 0; u < 8; u++) {
      const int s = s8 + u;
      const int p = u & 1;                   // s8 is even*8 -> s&1 == u&1
      // prefetch next step's xg (s+1 <= 280 < Tn always here)
      const int tn_ = dir ? (Tn - 2 - s) : (s + 1);
      const float xgn = xwd[(srow + tn_) * Gn + q * Hn + j];
      // matvec over K-slice: 4 gate chains x 32 FMA
      float a0 = 0.f, a1 = 0.f, a2 = 0.f, a3 = 0.f;
      const float* hs = &hl[p][36 * q];
#pragma unroll
      for (int i = 0; i < 8; i++) {
        const float4 h4 = *(const float4*)&hs[4 * i];
        a0 = fmaf(w[0][4 * i + 0], h4.x, a0);
        a0 = fmaf(w[0][4 * i + 1], h4.y, a0);
        a0 = fmaf(w[0][4 * i + 2], h4.z, a0);
        a0 = fmaf(w[0][4 * i + 3], h4.w, a0);
        a1 = fmaf(w[1][4 * i + 0], h4.x, a1);
        a1 = fmaf(w[1][4 * i + 1], h4.y, a1);
        a1 = fmaf(w[1][4 * i + 2], h4.z, a1);
        a1 = fmaf(w[1][4 * i + 3], h4.w, a1);
        a2 = fmaf(w[2][4 * i + 0], h4.x, a2);
        a2 = fmaf(w[2][4 * i + 1], h4.y, a2);
        a2 = fmaf(w[2][4 * i + 2], h4.z, a2);
        a2 = fmaf(w[2][4 * i + 3], h4.w, a2);
        a3 = fmaf(w[3][4 * i + 0], h4.x, a3);
        a3 = fmaf(w[3][4 * i + 1], h4.y, a3);
        a3 = fmaf(w[3][4 * i + 2], h4.z, a3);
        a3 = fmaf(w[3][4 * i + 3], h4.w, a3);
      }
      // add xw (gate q) exactly once per quad, then butterfly-reduce
      a0 += (q == 0) ? xg : 0.f;
      a1 += (q == 1) ? xg : 0.f;
      a2 += (q == 2) ? xg : 0.f;
      a3 += (q == 3) ? xg : 0.f;
      a0 += __shfl_xor(a0, 1); a0 += __shfl_xor(a0, 2);
      a1 += __shfl_xor(a1, 1); a1 += __shfl_xor(a1, 2);
      a2 += __shfl_xor(a2, 1); a2 += __shfl_xor(a2, 2);
      a3 += __shfl_xor(a3, 1); a3 += __shfl_xor(a3, 2);
      // state update (redundant in quad; bitwise-identical inputs)
      const float iv = sigm(a0);
      const float fv = sigm(a1);
      const float gv = tanhf_fast(a2);
      const float ov = sigm(a3);
      c = fv * c + iv * gv;
      const float hv = ov * tanhf_fast(c);
      if (q == 0) hl[p ^ 1][jpad] = hv;
      hbuf[u] = hv;                          // static index after unroll
      __syncthreads();
      xg = xgn;
    }
    // batched hout stores: one drain's worth per 8 steps
    if (q == 0) {
#pragma unroll
      for (int u = 0; u < 8; u++) {
        const int ss = s8 + u;
        const int tt = dir ? (Tn - 1 - ss) : ss;
        hop[(size_t)tt * 256] = hbuf[u];
      }
    }
  }
  // tail step s = 280 (parity 0)
  {
    float a0 = 0.f, a1 = 0.f, a2 = 0.f, a3 = 0.f;
    const float* hs = &hl[0][36 * q];
#pragma unroll
    for (int i = 0; i < 8; i++) {
      const float4 h4 = *(const float4*)&hs[4 * i];
      a0 = fmaf(w[0][4 * i + 0], h4.x, a0);
      a0 = fmaf(w[0][4 * i + 1], h4.y, a0);
      a0 = fmaf(w[0][4 * i + 2], h4.z, a0);
      a0 = fmaf(w[0][4 * i + 3], h4.w, a0);
      a1 = fmaf(w[1][4 * i + 0], h4.x, a1);
      a1 = fmaf(w[1][4 * i + 1], h4.y, a1);
      a1 = fmaf(w[1][4 * i + 2], h4.z, a1);
      a1 = fmaf(w[1][4 * i + 3], h4.w, a1);
      a2 = fmaf(w[2][4 * i + 0], h4.x, a2);
      a2 = fmaf(w[2][4 * i + 1], h4.y, a2);
      a2 = fmaf(w[2][4 * i + 2], h4.z, a2);
      a2 = fmaf(w[2][4 * i + 3], h4.w, a2);
      a3 = fmaf(w[3][4 * i + 0], h4.x, a3);
      a3 = fmaf(w[3][4 * i + 1], h4.y, a3);
      a3 = fmaf(w[3][4 * i + 2], h4.z, a3);
      a3 = fmaf(w[3][4 * i + 3], h4.w, a3);
    }
    a0 += (q == 0) ? xg : 0.f;
    a1 += (q == 1) ? xg : 0.f;
    a2 += (q == 2) ? xg : 0.f;
    a3 += (q == 3) ? xg : 0.f;
    a0 += __shfl_xor(a0, 1); a0 += __shfl_xor(a0, 2);
    a1 += __shfl_xor(a1, 1); a1 += __shfl_xor(a1, 2);
    a2 += __shfl_xor(a2, 1); a2 += __shfl_xor(a2, 2);
    a3 += __shfl_xor(a3, 1); a3 += __shfl_xor(a3, 2);
    const float iv = sigm(a0);
    const float fv = sigm(a1);
    const float gv = tanhf_fast(a2);
    const float ov = sigm(a3);
    c = fv * c + iv * gv;
    const float hv = ov * tanhf_fast(c);
    if (q == 0) {
      const int tt = dir ? 0 : (Tn - 1);
      hop[(size_t)tt * 256] = hv;
    }
  }
}

// ---------------------------------------------------------------------------
// a[m] = u[m][0:256] . v[0:256] — one wave per row.
// ---------------------------------------------------------------------------
__global__ __launch_bounds__(256) void dot_v_kernel(
    const float* __restrict__ u, const float* __restrict__ v,
    float* __restrict__ a, int MC)
{
  const int lane = threadIdx.x & 63;
  const int row  = blockIdx.x * 4 + (threadIdx.x >> 6);
  if (row >= MC) return;
  const float4 uv = ((const float4*)(u + (size_t)row * 256))[lane];
  const float4 vv = ((const float4*)v)[lane];
  float p = uv.x * vv.x + uv.y * vv.y + uv.z * vv.z + uv.w * vv.w;
#pragma unroll
  for (int off = 32; off > 0; off >>= 1) p += __shfl_down(p, off);
  if (lane == 0) a[row] = p;
}

// ---------------------------------------------------------------------------
// softmax over T + pooling (chunk-local).
// ---------------------------------------------------------------------------
__global__ __launch_bounds__(256) void attn_pool(
    const float* __restrict__ a, const float* __restrict__ h1,
    float* __restrict__ wout)
{
  const int b    = blockIdx.x;
  const int tid  = threadIdx.x;
  const int lane = tid & 63;
  const int wid  = tid >> 6;
  __shared__ float sa[Tn];
  __shared__ float red[8];

  float lmax = -3.4e38f;
  for (int t = tid; t < Tn; t += 256) {
    const float x = a[(size_t)b * Tn + t];
    sa[t] = x;
    lmax  = fmaxf(lmax, x);
  }
#pragma unroll
  for (int off = 1; off < 64; off <<= 1) lmax = fmaxf(lmax, __shfl_xor(lmax, off));
  if (lane == 0) red[wid] = lmax;
  __syncthreads();
  const float bmax = fmaxf(fmaxf(red[0], red[1]), fmaxf(red[2], red[3]));

  float lsum = 0.f;
  for (int t = tid; t < Tn; t += 256) {
    const float e = __expf(sa[t] - bmax);
    sa[t] = e;
    lsum += e;
  }
#pragma unroll
  for (int off = 1; off < 64; off <<= 1) lsum += __shfl_xor(lsum, off);
  if (lane == 0) red[4 + wid] = lsum;
  __syncthreads();
  const float inv = 1.f / (red[4] + red[5] + red[6] + red[7]);

  float acc = 0.f;
  const float* hb = h1 + (size_t)b * Tn * 256 + tid;
  for (int t = 0; t < Tn; t++) acc += sa[t] * hb[(size_t)t * 256];
  wout[(size_t)b * 256 + tid] = acc * inv;
}

// ---------------------------------------------------------------------------
extern "C" void kernel_launch(void* const* d_in, const int* in_sizes, int n_in,
                              void* d_out, int out_size, void* d_ws, size_t ws_size,
                              hipStream_t stream)
{
  const float* X      = (const float*)d_in[0];
  const float* w_ih0f = (const float*)d_in[1];
  const float* w_hh0f = (const float*)d_in[2];
  const float* b_ih0f = (const float*)d_in[3];
  const float* b_hh0f = (const float*)d_in[4];
  const float* w_ih0b = (const float*)d_in[5];
  const float* w_hh0b = (const float*)d_in[6];
  const float* b_ih0b = (const float*)d_in[7];
  const float* b_hh0b = (const float*)d_in[8];
  const float* w_ih1f = (const float*)d_in[9];
  const float* w_hh1f = (const float*)d_in[10];
  const float* b_ih1f = (const float*)d_in[11];
  const float* b_hh1f = (const float*)d_in[12];
  const float* w_ih1b = (const float*)d_in[13];
  const float* w_hh1b = (const float*)d_in[14];
  const float* b_ih1b = (const float*)d_in[15];
  const float* b_hh1b = (const float*)d_in[16];
  const float* att_W  = (const float*)d_in[17];
  const float* att_v  = (const float*)d_in[18];
  const float* head_W = (const float*)d_in[19];
  const float* head_b = (const float*)d_in[20];

  // largest chunk size fitting ws_size (deterministic across calls)
  int Bc = 8;
  {
    const int cands[7] = {512, 256, 128, 64, 32, 16, 8};
    for (int i = 0; i < 7; i++) {
      const size_t mc   = (size_t)cands[i] * Tn;
      const size_t need = 4ull * ((size_t)512 * 256 + mc * 1537);
      if (need <= ws_size) { Bc = cands[i]; break; }
    }
  }
  const size_t MCs = (size_t)Bc * Tn;
  const int    MC  = (int)MCs;

  float* wgt = (float*)d_ws;               // [512][256] persistent
  float* xwc = wgt + (size_t)512 * 256;    // [2][MC][512]
  float* h0c = xwc + 2 * MCs * Gn;         // [MC][256]
  float* h1c = h0c + MCs * 256;            // [MC][256]
  float* ac  = h1c + MCs * 256;            // [MC]
  float* u   = xwc;                        // reuse (xw dead by phase 5)

  const dim3 blk(256);
  const int  mt = (MC + 127) / 128;
  const dim3 gXW(mt, Gn / 128);            // (., 4)
  const dim3 gU(mt, 256 / 128);            // (., 2)
  const int  nch = Bn / Bc;

  for (int ch = 0; ch < nch; ch++) {
    const float* Xc   = X + (size_t)ch * Bc * Cn * Tn;
    float*       wgtc = wgt + (size_t)ch * Bc * 256;

    // 1) layer-0 input projections (transpose fused), both biases folded
    gemm_tile<1, 0, 0, 2><<<gXW, blk, 0, stream>>>(Xc, w_ih0f, b_ih0f, b_hh0f,
                                                   xwc, MC, Gn, Cn, Gn);
    gemm_tile<1, 0, 0, 2><<<gXW, blk, 0, stream>>>(Xc, w_ih0b, b_ih0b, b_hh0b,
                                                   xwc + MCs * Gn, MC, Gn, Cn, Gn);
    // 2) layer-0 recurrence
    lstm_rec3<<<dim3(Bc, 2), dim3(512), 0, stream>>>(xwc, w_hh0f, w_hh0b, h0c, MC);
    // 3) layer-1 input projections
    gemm_tile<0, 0, 0, 2><<<gXW, blk, 0, stream>>>(h0c, w_ih1f, b_ih1f, b_hh1f,
                                                   xwc, MC, Gn, 256, Gn);
    gemm_tile<0, 0, 0, 2><<<gXW, blk, 0, stream>>>(h0c, w_ih1b, b_ih1b, b_hh1b,
                                                   xwc + MCs * Gn, MC, Gn, 256, Gn);
    // 4) layer-1 recurrence
    lstm_rec3<<<dim3(Bc, 2), dim3(512), 0, stream>>>(xwc, w_hh1f, w_hh1b, h1c, MC);
    // 5) u = tanh(h1 @ att_W)
    gemm_tile<0, 1, 1, 0><<<gU, blk, 0, stream>>>(h1c, att_W, nullptr, nullptr,
                                                  u, MC, 256, 256, 256);
    // 6) a = u . att_v
    dot_v_kernel<<<dim3((MC + 3) / 4), blk, 0, stream>>>(u, att_v, ac, MC);
    // 7) softmax + pooling into this chunk's wgt slice
    attn_pool<<<dim3(Bc), blk, 0, stream>>>(ac, h1c, wgtc);
  }
  // 8) head
  gemm_tile<0, 0, 0, 1><<<dim3((Bn + 127) / 128, (NCLS + 127) / 128), blk, 0, stream>>>(
      wgt, head_W, head_b, nullptr, (float*)d_out, Bn, NCLS, 256, NCLS);
}